// Round 12
// baseline (33.129 us; speedup 1.0000x reference)
//
#include <hip/hip_runtime.h>
#include <math.h>

#define D 64
#define DH 32

typedef __attribute__((ext_vector_type(8))) short bf16x8;   // MFMA A/B frag (4 VGPRs)
typedef __attribute__((ext_vector_type(4))) float f32x4;    // MFMA C/D frag

// fp32 -> bf16 RNE
static __device__ __forceinline__ unsigned short f2b(float f) {
    unsigned int u = __builtin_bit_cast(unsigned int, f);
    u += 0x7FFFu + ((u >> 16) & 1u);
    return (unsigned short)(u >> 16);
}
static __device__ __forceinline__ unsigned int pack_b2(float a, float b) {
    return (unsigned int)f2b(a) | ((unsigned int)f2b(b) << 16);
}
// A&S 7.1.26 erf (|err| < 1.5e-7): 1 rcp + 1 exp + ~10 fma, no branches
static __device__ __forceinline__ float gelu_fast(float v) {
    const float ax = fabsf(v) * 0.70710678118654752f;
    const float t  = __builtin_amdgcn_rcpf(fmaf(0.3275911f, ax, 1.0f));
    float poly = fmaf(1.061405429f, t, -1.453152027f);
    poly = fmaf(poly, t, 1.421413741f);
    poly = fmaf(poly, t, -0.284496736f);
    poly = fmaf(poly, t, 0.254829592f);
    poly *= t;
    float er = fmaf(-poly, __expf(-ax * ax), 1.0f);
    er = copysignf(er, v);
    return 0.5f * v * (1.0f + er);
}

// ---------------------------------------------------------------------------
// Softmax over each row-segment sums to exactly 1, so
//   out[i] = has_edge(i) ? h[i]*(1+peak[i]) + bias : bias
// att_src/att_dst/leaky-relu/segment-softmax cancel analytically.
// ---------------------------------------------------------------------------
__global__ void edge_flag_kernel(const int* __restrict__ row,
                                 unsigned char* __restrict__ flag, int E) {
    const int base = (blockIdx.x * blockDim.x + threadIdx.x) * 8;
    if (base + 7 < E) {
        const int4 a = *(const int4*)(row + base);
        const int4 b = *(const int4*)(row + base + 4);
        flag[a.x] = 1; flag[a.y] = 1; flag[a.z] = 1; flag[a.w] = 1;
        flag[b.x] = 1; flag[b.y] = 1; flag[b.z] = 1; flag[b.w] = 1;
    } else if (base < E) {
        for (int j = base; j < E; ++j) flag[row[j]] = 1;
    }
}

// ---------------------------------------------------------------------------
// Main: persistent grid-stride kernel, 1024 blocks x 4 waves (4 blocks/CU,
// 16 waves/CU, 4 waves/SIMD -- TLP to hide the latency-bound chain).
// Tile = 64 nodes (16/wave).  Prologue: each wave self-packs weight frags
// from raw Wlin/W1/bias/b1/W2 (L2-hot coalesced gathers).  Hot loop:
// x-prefetch(next) || {cvt, 8+4 MFMA, wave-private LDS roundtrip, gelu-dot,
// epilogue store}.  No barriers anywhere.
// ---------------------------------------------------------------------------
__global__ __launch_bounds__(256) void gat_mfma7(
    const float* __restrict__ x, const unsigned char* __restrict__ flag,
    const float* __restrict__ Wlin, const float* __restrict__ bias,
    const float* __restrict__ W1, const float* __restrict__ b1,
    const float* __restrict__ W2, const float* __restrict__ b2,
    float* __restrict__ out, int N, int ntiles)
{
    __shared__ unsigned short sH[4][16][72];   // per-wave h bf16, 9 KB

    const int tid  = threadIdx.x;
    const int wv   = tid >> 6;
    const int lane = tid & 63;
    const int q    = lane >> 4;
    const int m    = lane & 15;

    // ---- prologue: self-pack weight fragments into registers ----
    bf16x8 aw[4][2], aw1[2][2];
#pragma unroll
    for (int nt = 0; nt < 4; ++nt)
#pragma unroll
        for (int ks = 0; ks < 2; ++ks) {
            bf16x8 a;
#pragma unroll
            for (int j = 0; j < 8; ++j)
                a[j] = (short)f2b(Wlin[(32 * ks + 8 * q + j) * D + 16 * nt + m]);
            aw[nt][ks] = a;
        }
#pragma unroll
    for (int nt = 0; nt < 2; ++nt)
#pragma unroll
        for (int ks = 0; ks < 2; ++ks) {
            bf16x8 a;
#pragma unroll
            for (int j = 0; j < 8; ++j)
                a[j] = (short)f2b(W1[(32 * ks + 8 * q + j) * DH + 16 * nt + m]);
            aw1[nt][ks] = a;
        }
    f32x4 b1v0, b1v1, w2v0, w2v1;
    f32x4 biasv[4];
#pragma unroll
    for (int r = 0; r < 4; ++r) {
        b1v0[r] = b1[4 * q + r];
        b1v1[r] = b1[16 + 4 * q + r];
        w2v0[r] = W2[4 * q + r];
        w2v1[r] = W2[16 + 4 * q + r];
#pragma unroll
        for (int nt = 0; nt < 4; ++nt)
            biasv[nt][r] = bias[16 * nt + 4 * q + r];
    }
    const float b2s = b2[0];

    int t = blockIdx.x;
    if (t >= ntiles) return;

    // ---- load tile t (cur) ----
    float4 cu0, cu1, cu2, cu3; unsigned char cfl;
    {
        int g = t * 64 + wv * 16 + m; if (g > N - 1) g = N - 1;
        const float* px = x + (size_t)g * D + 8 * q;
        cu0 = *(const float4*)(px);      cu1 = *(const float4*)(px + 4);
        cu2 = *(const float4*)(px + 32); cu3 = *(const float4*)(px + 36);
        cfl = flag[g];
    }

    while (true) {
        const int tn = t + gridDim.x;
        const bool more = tn < ntiles;
        // ---- prefetch tile tn (issued before compute; drains during MFMA) ----
        float4 nu0, nu1, nu2, nu3; unsigned char nfl = 0;
        if (more) {
            int g = tn * 64 + wv * 16 + m; if (g > N - 1) g = N - 1;
            const float* px = x + (size_t)g * D + 8 * q;
            nu0 = *(const float4*)(px);      nu1 = *(const float4*)(px + 4);
            nu2 = *(const float4*)(px + 32); nu3 = *(const float4*)(px + 36);
            nfl = flag[g];
        }

        // ---- cvt x -> bf16 B-frags ----
        uint4 pk0, pk1;
        pk0.x = pack_b2(cu0.x, cu0.y); pk0.y = pack_b2(cu0.z, cu0.w);
        pk0.z = pack_b2(cu1.x, cu1.y); pk0.w = pack_b2(cu1.z, cu1.w);
        pk1.x = pack_b2(cu2.x, cu2.y); pk1.y = pack_b2(cu2.z, cu2.w);
        pk1.z = pack_b2(cu3.x, cu3.y); pk1.w = pack_b2(cu3.z, cu3.w);
        const bf16x8 bx0 = __builtin_bit_cast(bf16x8, pk0);
        const bf16x8 bx1 = __builtin_bit_cast(bf16x8, pk1);

        // ---- GEMM1: h^T = W^T @ x^T ----
        f32x4 accH[4];
#pragma unroll
        for (int nt = 0; nt < 4; ++nt) accH[nt] = (f32x4){0.f, 0.f, 0.f, 0.f};
#pragma unroll
        for (int nt = 0; nt < 4; ++nt)
            accH[nt] = __builtin_amdgcn_mfma_f32_16x16x32_bf16(aw[nt][0], bx0, accH[nt], 0, 0, 0);
#pragma unroll
        for (int nt = 0; nt < 4; ++nt)
            accH[nt] = __builtin_amdgcn_mfma_f32_16x16x32_bf16(aw[nt][1], bx1, accH[nt], 0, 0, 0);
        // lane holds h[node = t*64+wv*16+m][hcol = 16nt+4q+r]

        // ---- h -> wave-private LDS roundtrip (bf16), relayout for GEMM2 ----
        asm volatile("" ::: "memory");
#pragma unroll
        for (int nt = 0; nt < 4; ++nt) {
            uint2 pk;
            pk.x = pack_b2(accH[nt][0], accH[nt][1]);
            pk.y = pack_b2(accH[nt][2], accH[nt][3]);
            *(uint2*)&sH[wv][m][16 * nt + 4 * q] = pk;
        }
        asm volatile("" ::: "memory");
        const bf16x8 a20 = *(const bf16x8*)&sH[wv][m][8 * q];
        const bf16x8 a21 = *(const bf16x8*)&sH[wv][m][32 + 8 * q];

        // ---- GEMM2: t^T = W1^T @ h^T ----
        f32x4 acc20 = b1v0, acc21 = b1v1;
        acc20 = __builtin_amdgcn_mfma_f32_16x16x32_bf16(aw1[0][0], a20, acc20, 0, 0, 0);
        acc20 = __builtin_amdgcn_mfma_f32_16x16x32_bf16(aw1[0][1], a21, acc20, 0, 0, 0);
        acc21 = __builtin_amdgcn_mfma_f32_16x16x32_bf16(aw1[1][0], a20, acc21, 0, 0, 0);
        acc21 = __builtin_amdgcn_mfma_f32_16x16x32_bf16(aw1[1][1], a21, acc21, 0, 0, 0);

        // ---- peak: pp = sum gelu(t)*W2; reduce over 4 q-groups ----
        float pp = 0.f;
#pragma unroll
        for (int r = 0; r < 4; ++r) {
            pp = fmaf(gelu_fast(acc20[r]), w2v0[r], pp);
            pp = fmaf(gelu_fast(acc21[r]), w2v1[r], pp);
        }
        pp += __shfl_xor(pp, 16);
        pp += __shfl_xor(pp, 32);
        const float sg = __builtin_amdgcn_rcpf(1.f + __expf(-(pp + b2s)));
        const float scale = (cfl != 0) ? (1.f + sg) : 0.f;

        // ---- epilogue: out = h*scale + bias ----
        const int g = t * 64 + wv * 16 + m;
        if (g < N) {
            float* po = out + (size_t)g * D + 4 * q;
#pragma unroll
            for (int nt = 0; nt < 4; ++nt) {
                f32x4 o;
#pragma unroll
                for (int r = 0; r < 4; ++r)
                    o[r] = fmaf(accH[nt][r], scale, biasv[nt][r]);
                *(f32x4*)(po + 16 * nt) = o;
            }
        }

        if (!more) break;
        cu0 = nu0; cu1 = nu1; cu2 = nu2; cu3 = nu3; cfl = nfl;
        t = tn;
    }
}

extern "C" void kernel_launch(void* const* d_in, const int* in_sizes, int n_in,
                              void* d_out, int out_size, void* d_ws, size_t ws_size,
                              hipStream_t stream) {
    const float* x    = (const float*)d_in[0];
    const int*   eidx = (const int*)d_in[1];   // [2, E]: first E entries = row
    const float* Wlin = (const float*)d_in[2];
    // d_in[3] att_src, d_in[4] att_dst cancel (segment softmax sums to 1)
    const float* bias = (const float*)d_in[5];
    const float* W1   = (const float*)d_in[6];
    const float* b1   = (const float*)d_in[7];
    const float* W2   = (const float*)d_in[8];
    const float* b2   = (const float*)d_in[9];
    float* out = (float*)d_out;

    const int N = in_sizes[0] / D;
    const int E = in_sizes[1] / 2;

    unsigned char* flag = (unsigned char*)d_ws;

    const int ntiles  = (N + 63) / 64;
    const int nblocks = (ntiles < 1024) ? ntiles : 1024;   // 4 blocks/CU -> 16 waves/CU

    hipMemsetAsync(flag, 0, (size_t)N, stream);
    edge_flag_kernel<<<(E / 8 + 255) / 256, 256, 0, stream>>>(eidx, flag, E);
    gat_mfma7<<<nblocks, 256, 0, stream>>>(x, flag, Wlin, bias, W1, b1, W2, b2,
                                           out, N, ntiles);
}